// Round 2
// 535.429 us; speedup vs baseline: 1.0061x; 1.0061x over previous
//
#include <hip/hip_runtime.h>

#define MDIM 8192
#define NDIM 4096
#define KDIM 4096

typedef __attribute__((ext_vector_type(8))) short short8;    // 8 bf16 = 4 VGPRs
typedef __attribute__((ext_vector_type(4))) float floatx4;   // MFMA C/D

typedef const __attribute__((address_space(1))) unsigned int* gptr_t;
typedef __attribute__((address_space(3))) unsigned int* lptr_t;

// fp32 -> bf16 round-to-nearest-even (bit trick; NaN irrelevant here)
static __device__ __forceinline__ unsigned short f2bf(float f) {
    union { float f; unsigned int u; } a; a.f = f;
    unsigned int r = a.u + 0x7FFFu + ((a.u >> 16) & 1u);
    return (unsigned short)(r >> 16);
}

// ---- kernel 1: x (fp32) -> bf16, vectorized grid-stride (unchanged) ----
__global__ void cvt_x_kernel(const float* __restrict__ x, unsigned short* __restrict__ xb) {
    int idx = blockIdx.x * blockDim.x + threadIdx.x;
    int stride = gridDim.x * blockDim.x;
    const float4* x4 = (const float4*)x;
    ushort4* o4 = (ushort4*)xb;
    const int n4 = (MDIM * KDIM) / 4;
    for (int i = idx; i < n4; i += stride) {
        float4 v = x4[i];
        ushort4 o;
        o.x = f2bf(v.x); o.y = f2bf(v.y); o.z = f2bf(v.z); o.w = f2bf(v.w);
        o4[i] = o;
    }
}

// ---- kernel 2: W (fp32) -> sign(W) bf16 (+1/-1/0 exact), fused sum(|W|) (unchanged) ----
__global__ void cvt_w_kernel(const float* __restrict__ w, unsigned short* __restrict__ sb,
                             float* __restrict__ sum) {
    int idx = blockIdx.x * blockDim.x + threadIdx.x;
    int stride = gridDim.x * blockDim.x;
    const float4* w4 = (const float4*)w;
    ushort4* o4 = (ushort4*)sb;
    const int n4 = (NDIM * KDIM) / 4;
    float s = 0.f;
    for (int i = idx; i < n4; i += stride) {
        float4 v = w4[i];
        ushort4 o;
        o.x = (unsigned short)(v.x > 0.f ? 0x3F80 : (v.x < 0.f ? 0xBF80 : 0));
        o.y = (unsigned short)(v.y > 0.f ? 0x3F80 : (v.y < 0.f ? 0xBF80 : 0));
        o.z = (unsigned short)(v.z > 0.f ? 0x3F80 : (v.z < 0.f ? 0xBF80 : 0));
        o.w = (unsigned short)(v.w > 0.f ? 0x3F80 : (v.w < 0.f ? 0xBF80 : 0));
        s += fabsf(v.x) + fabsf(v.y) + fabsf(v.z) + fabsf(v.w);
        o4[i] = o;
    }
    #pragma unroll
    for (int off = 32; off > 0; off >>= 1) s += __shfl_down(s, off, 64);
    __shared__ float red[4];
    int lane = threadIdx.x & 63, wv = threadIdx.x >> 6;
    if (lane == 0) red[wv] = s;
    __syncthreads();
    if (threadIdx.x == 0) atomicAdd(sum, red[0] + red[1] + red[2] + red[3]);
}

// ================= kernel 3: 256x256-tile 8-phase bf16 GEMM =================
// C[m,n] = scale * sum_k A[m,k]*B[n,k], A: 8192x4096 bf16, B: 4096x4096 bf16.
//
// Structure (8-phase / counted-vmcnt template, T1+T2+T3+T4+T5):
//  - 512 thr = 8 waves, wave grid 2(M)x4(N); per-wave C = 128x64 = acc[8][4].
//  - BK=64 split into two k-halves (kb0/kb1); each half of A/B is a separate
//    contiguous 16KB LDS buffer [256 rows][32 cols] so global_load_lds can fill it.
//    4 halves x 2 tile-parities x (A,B) = 128 KB LDS, double-buffered by tile parity.
//  - Phase (kb, npair): 16 MFMA (8 m-frags x 2 n-frags); A-frags loaded at npair==0
//    and reused at npair==1 -> 24 ds_read_b128 per tile per wave vs 64 MFMA.
//  - Stage schedule per iteration (tiles t=2it parity-0, t+1 parity-1):
//      p1: kh1pair(t+1)->[1][1]   p3: Akh0(t+2)->A[0][0]   p4: Bkh0(t+2)->B[0][0] +vmcnt(4)
//      p5: kh1pair(t+2)->[1][0]   p7: Akh0(t+3)->A[0][1]   p8: Bkh0(t+3)->B[0][1] +vmcnt(4)
//    Steady state: 12 outstanding at each vmcnt(4); wait-to-4 retires the 8 oldest
//    (carried kh0-pair + the kh1-pair staged 3 phases earlier), so every buffer is
//    provably resident behind a (vmcnt, barrier) pair before any wave reads it.
//    4 loads (next tile's kh0) stay in flight across every barrier; the main loop
//    never drains vmcnt to 0 (T4). All waves run the same vmcnt+barrier sequence.
//  - Bank conflicts: kh rows are 64B (4 x 16B chunks). Physical chunk =
//    kc ^ ((row>>1)&3), applied by pre-swizzling the *global source* address
//    (LDS dest stays linear, as global_load_lds requires). A 16-lane fragment
//    group then covers each (row-parity, chunk) bank-quad exactly 2x -> 2-way = free.
//  - T1: XCD-aware block swizzle (512 blocks % 8 == 0): each XCD owns a contiguous
//    1024-row slab of M -> A-panels stay L2-resident per XCD.

#define MEMBAR() asm volatile("" ::: "memory")
#define BARRIER() do { MEMBAR(); __builtin_amdgcn_s_barrier(); MEMBAR(); } while (0)
#define VMCNT4() asm volatile("s_waitcnt vmcnt(4)" ::: "memory")
#define VMCNT0() asm volatile("s_waitcnt vmcnt(0)" ::: "memory")
#define PRIO1() __builtin_amdgcn_s_setprio(1)
#define PRIO0() __builtin_amdgcn_s_setprio(0)

// stage one 16KB k-half (256 rows x 32 cols bf16): 2 global_load_lds x 512 thr x 16B.
// src is the per-thread pre-swizzled pointer (row t>>2, chunk (t&3)^((t>>3)&3));
// rows 128..255 keep the same chunk swizzle (row+128 doesn't change ((row>>1)&3)).
static __device__ __forceinline__ void stage_half(const unsigned short* src,
                                                  unsigned short* l, int wv) {
    __builtin_amdgcn_global_load_lds((gptr_t)(src), (lptr_t)(l + wv * 512), 16, 0, 0);
    __builtin_amdgcn_global_load_lds((gptr_t)(src + (size_t)128 * KDIM),
                                     (lptr_t)(l + 4096 + wv * 512), 16, 0, 0);
}

static __device__ __forceinline__ void ld_af(short8 (&af)[8], const unsigned short* base, int aoff) {
    #pragma unroll
    for (int m = 0; m < 8; ++m) af[m] = *(const short8*)(base + aoff + m * 512);
}
static __device__ __forceinline__ void ld_bf(short8 (&bf)[2], const unsigned short* base, int boff) {
    bf[0] = *(const short8*)(base + boff);
    bf[1] = *(const short8*)(base + boff + 512);
}
template <int NP>
static __device__ __forceinline__ void mfma16(floatx4 (&acc)[8][4], const short8 (&af)[8],
                                              const short8 (&bf)[2]) {
    #pragma unroll
    for (int m = 0; m < 8; ++m) {
        acc[m][NP * 2]     = __builtin_amdgcn_mfma_f32_16x16x32_bf16(af[m], bf[0], acc[m][NP * 2], 0, 0, 0);
        acc[m][NP * 2 + 1] = __builtin_amdgcn_mfma_f32_16x16x32_bf16(af[m], bf[1], acc[m][NP * 2 + 1], 0, 0, 0);
    }
}

__global__ __launch_bounds__(512, 2) void gemm_kernel(
    const unsigned short* __restrict__ A,   // MDIM x KDIM bf16
    const unsigned short* __restrict__ B,   // NDIM x KDIM bf16 (sign weights)
    float* __restrict__ C,                  // MDIM x NDIM fp32
    const float* __restrict__ sum)          // sum(|W|); scale = sum / (N*K)
{
    // 128 KB LDS, function-scope (file-scope __shared__ was the round-1 suspect)
    __shared__ __align__(16) unsigned short As[2][2][8192];   // [kb][parity][256*32]
    __shared__ __align__(16) unsigned short Bs[2][2][8192];

    const int t = threadIdx.x;
    const int lane = t & 63;
    const int wv = t >> 6;            // wave 0..7
    const int wr = wv >> 2;           // wave M-row 0..1 -> 128-row slab
    const int wc = wv & 3;            // wave N-col 0..3 -> 64-col slab

    // T1: XCD swizzle. 512 blocks, 8 XCDs, 64 blocks/XCD = 4 tile-rows x 16 cols.
    const int bid = blockIdx.x;
    const int lin = (bid & 7) * 64 + (bid >> 3);
    const int m0 = (lin >> 4) * 256;
    const int n0 = (lin & 15) * 256;

    // fragment-read constants: lane reads row (base+fr), k-chunk kc within a half;
    // physical chunk = kc ^ ((row>>1)&3) = kc ^ ((fr>>1)&3) since all row bases %16==0.
    const int fr = lane & 15;
    const int kc = lane >> 4;
    const int pk = ((kc ^ ((fr >> 1) & 3)) << 3);
    const int aoff = (wr * 128 + fr) * 32 + pk;
    const int boff = (wc * 64 + fr) * 32 + pk;

    // staging source: thread t covers row t>>2 (and +128), chunk (t&3)^((t>>3)&3)
    const int srow = t >> 2;
    const int schunk = ((t & 3) ^ ((t >> 3) & 3)) << 3;
    const unsigned short* srcA = A + (size_t)(m0 + srow) * KDIM + schunk;
    const unsigned short* srcB = B + (size_t)(n0 + srow) * KDIM + schunk;

    unsigned short* As00 = &As[0][0][0]; unsigned short* As01 = &As[0][1][0];
    unsigned short* As10 = &As[1][0][0]; unsigned short* As11 = &As[1][1][0];
    unsigned short* Bs00 = &Bs[0][0][0]; unsigned short* Bs01 = &Bs[0][1][0];
    unsigned short* Bs10 = &Bs[1][0][0]; unsigned short* Bs11 = &Bs[1][1][0];

    floatx4 acc[8][4] = {};
    short8 af[8];
    short8 bf[2];

    // ---- prologue: tile0 complete + tile1 kh0; leave tile1's kh0 (4 loads) in flight
    stage_half(srcA +  0, As00, wv);   // Akh0(0)
    stage_half(srcB +  0, Bs00, wv);   // Bkh0(0)
    stage_half(srcA + 32, As10, wv);   // Akh1(0)
    stage_half(srcB + 32, Bs10, wv);   // Bkh1(0)
    stage_half(srcA + 64, As01, wv);   // Akh0(1)
    stage_half(srcB + 64, Bs01, wv);   // Bkh0(1)
    VMCNT4();                           // tile0 fully resident
    BARRIER();

    // ---- main loop: 31 steady iterations of 2 K-tiles (k0 = element offset)
    #pragma unroll 1
    for (int it = 0; it < 31; ++it) {
        const int k0 = it * 128;
        // p1: tile t (kb0, n01)
        ld_af(af, As00, aoff); ld_bf(bf, Bs00, boff);
        stage_half(srcA + k0 + 96, As11, wv);  stage_half(srcB + k0 + 96, Bs11, wv);
        BARRIER(); PRIO1(); mfma16<0>(acc, af, bf); PRIO0(); BARRIER();
        // p2: (kb0, n23) — af reuse
        ld_bf(bf, Bs00, boff + 1024);
        BARRIER(); PRIO1(); mfma16<1>(acc, af, bf); PRIO0(); BARRIER();
        // p3: (kb1, n01)
        ld_af(af, As10, aoff); ld_bf(bf, Bs10, boff);
        stage_half(srcA + k0 + 128, As00, wv);
        BARRIER(); PRIO1(); mfma16<0>(acc, af, bf); PRIO0(); BARRIER();
        // p4: (kb1, n23) + counted vmcnt
        ld_bf(bf, Bs10, boff + 1024);
        stage_half(srcB + k0 + 128, Bs00, wv);
        VMCNT4();
        BARRIER(); PRIO1(); mfma16<1>(acc, af, bf); PRIO0(); BARRIER();
        // p5: tile t+1 (kb0, n01)
        ld_af(af, As01, aoff); ld_bf(bf, Bs01, boff);
        stage_half(srcA + k0 + 160, As10, wv);  stage_half(srcB + k0 + 160, Bs10, wv);
        BARRIER(); PRIO1(); mfma16<0>(acc, af, bf); PRIO0(); BARRIER();
        // p6
        ld_bf(bf, Bs01, boff + 1024);
        BARRIER(); PRIO1(); mfma16<1>(acc, af, bf); PRIO0(); BARRIER();
        // p7
        ld_af(af, As11, aoff); ld_bf(bf, Bs11, boff);
        stage_half(srcA + k0 + 192, As01, wv);
        BARRIER(); PRIO1(); mfma16<0>(acc, af, bf); PRIO0(); BARRIER();
        // p8 + counted vmcnt
        ld_bf(bf, Bs11, boff + 1024);
        stage_half(srcB + k0 + 192, Bs01, wv);
        VMCNT4();
        BARRIER(); PRIO1(); mfma16<1>(acc, af, bf); PRIO0(); BARRIER();
    }

    // ---- peeled last iteration (tiles 62, 63): only kh1pair(63) left to stage
    ld_af(af, As00, aoff); ld_bf(bf, Bs00, boff);
    stage_half(srcA + 4064, As11, wv);  stage_half(srcB + 4064, Bs11, wv);
    BARRIER(); PRIO1(); mfma16<0>(acc, af, bf); PRIO0(); BARRIER();
    ld_bf(bf, Bs00, boff + 1024);
    BARRIER(); PRIO1(); mfma16<1>(acc, af, bf); PRIO0(); BARRIER();
    ld_af(af, As10, aoff); ld_bf(bf, Bs10, boff);
    BARRIER(); PRIO1(); mfma16<0>(acc, af, bf); PRIO0(); BARRIER();
    ld_bf(bf, Bs10, boff + 1024);
    VMCNT0();                           // drain: everything resident for tile 63
    BARRIER(); PRIO1(); mfma16<1>(acc, af, bf); PRIO0(); BARRIER();
    ld_af(af, As01, aoff); ld_bf(bf, Bs01, boff);
    BARRIER(); PRIO1(); mfma16<0>(acc, af, bf); PRIO0(); BARRIER();
    ld_bf(bf, Bs01, boff + 1024);
    BARRIER(); PRIO1(); mfma16<1>(acc, af, bf); PRIO0(); BARRIER();
    ld_af(af, As11, aoff); ld_bf(bf, Bs11, boff);
    BARRIER(); PRIO1(); mfma16<0>(acc, af, bf); PRIO0(); BARRIER();
    ld_bf(bf, Bs11, boff + 1024);
    BARRIER(); PRIO1(); mfma16<1>(acc, af, bf); PRIO0();

    // ---- epilogue: C/D layout col = lane&15, row = (lane>>4)*4 + reg
    const float scale = sum[0] * (1.0f / (float)((size_t)NDIM * KDIM));
    const int r0w = (lane >> 4) << 2;
    const int cB = n0 + wc * 64 + (lane & 15);
    #pragma unroll
    for (int m = 0; m < 8; ++m) {
        #pragma unroll
        for (int r = 0; r < 4; ++r) {
            const int row = m0 + wr * 128 + m * 16 + r0w + r;
            float* crow = C + (size_t)row * NDIM + cB;
            #pragma unroll
            for (int nn = 0; nn < 4; ++nn)
                crow[nn * 16] = acc[m][nn][r] * scale;
        }
    }
}

extern "C" void kernel_launch(void* const* d_in, const int* in_sizes, int n_in,
                              void* d_out, int out_size, void* d_ws, size_t ws_size,
                              hipStream_t stream) {
    const float* x = (const float*)d_in[0];   // 8192 x 4096 fp32
    const float* w = (const float*)d_in[1];   // 4096 x 4096 fp32
    float* out = (float*)d_out;               // 8192 x 4096 fp32

    // workspace layout: [x_bf16: 67,108,864 B][signW_bf16: 33,554,432 B][sum: 4 B]
    unsigned short* xb = (unsigned short*)d_ws;
    unsigned short* wb = (unsigned short*)((char*)d_ws + (size_t)MDIM * KDIM * 2);
    float* sum = (float*)((char*)d_ws + (size_t)MDIM * KDIM * 2 + (size_t)NDIM * KDIM * 2);

    hipMemsetAsync(sum, 0, sizeof(float), stream);  // ws is poisoned 0xAA each run
    cvt_x_kernel<<<2048, 256, 0, stream>>>(x, xb);
    cvt_w_kernel<<<2048, 256, 0, stream>>>(w, wb, sum);

    gemm_kernel<<<dim3(512), dim3(512), 0, stream>>>(xb, wb, out, sum);
}